// Round 4
// baseline (98.418 us; speedup 1.0000x reference)
//
#include <hip/hip_runtime.h>

// QuantumLayer: boson-sampling distribution + linear head.
//   x:[512,8] f32, thetas:[12] f32, W:[4368,10] f32, b:[10] f32 -> out:[512,10] f32
// Identities:
//   * Columns of U evolve independently under row-ops => evolve only cols 0..4.
//   * Glynn (16 terms, delta_0=+1) instead of Ryser (32 masks); per-term sign
//     folded into rs (sign^5 == sign); 2^-4 prefactor squared -> 1/256 in norm.
//   * Prefix factorization: s-tuples sharing (m0..m3) are contiguous runs
//     (m4 = m3..11). 16 Glynn 4-row products per prefix in 8 NAMED float4
//     regs (no runtime indexing => no scratch demotion; R2 lesson).
//   * R4: compile-time schedule. constexpr __constant__ table of the 1365
//     prefixes sorted v-DESCENDING (wave-uniform tail trip counts) + 1024
//     cost-balanced chunks (cost = 32+8*(12-v) ~ b128 count). TPB 1024,
//     grid 512 -> 2 blocks/CU, 32 waves/CU. Dual accumulators halve the
//     dependent-FMA chain.

#define MODES 12
#define NPH   5
#define KG    16
#define QG    8         // KG/2 packed pairs
#define S_TOT 4368
#define TPB   1024
#define NWAVE (TPB / 64)
#define NOUT  10
#define NPREF 1365

#define TWO_PI_F 6.28318530717958647692f
#define RS2      0.70710678118654752440f

// ---------------- compile-time schedule ----------------
constexpr int Cnk(int n, int r) {
  int p = 1;
  for (int i = 0; i < r; ++i) p = p * (n - i) / (i + 1);  // exact stepwise
  return p;
}

struct Tables {
  unsigned       pref[NPREF];   // sbase<<16 | m0<<12 | m1<<8 | m2<<4 | v
  unsigned short cstart[TPB + 1];
};

constexpr Tables make_tables() {
  Tables T{};
  int idx = 0;
  for (int v = 11; v >= 0; --v)
    for (int m0 = 0; m0 <= v; ++m0)
      for (int m1 = m0; m1 <= v; ++m1)
        for (int m2 = m1; m2 <= v; ++m2) {
          int sbase = 0;  // lex rank of (m0,m1,m2,v,v) in CWR(12,5)
          for (int q = 0;  q < m0; ++q) sbase += Cnk(15 - q, 4);
          for (int q = m0; q < m1; ++q) sbase += Cnk(14 - q, 3);
          for (int q = m1; q < m2; ++q) sbase += Cnk(13 - q, 2);
          for (int q = m2; q < v;  ++q) sbase += 12 - q;
          T.pref[idx++] = ((unsigned)sbase << 16) | ((unsigned)m0 << 12) |
                          ((unsigned)m1 << 8) | ((unsigned)m2 << 4) | (unsigned)v;
        }
  // cost-balanced chunks; cost(entry) = 32 + 8*(12-v)  (b128-load model)
  const long total = 78624;     // 1365*32 + 4368*8
  long cum = 0;
  int ci = 0;
  T.cstart[0] = 0;
  for (int i = 0; i < NPREF; ++i) {
    int v = (int)(T.pref[i] & 15u);
    cum += 32 + 8 * (12 - v);
    while (ci < TPB - 1 && cum * TPB >= (long)(ci + 1) * total)
      T.cstart[++ci] = (unsigned short)(i + 1);
  }
  while (ci < TPB) T.cstart[++ci] = NPREF;
  return T;
}

__constant__ Tables g_tab = make_tables();

// ---------------- device kernel ----------------
#define BFLY(i, j)                                                 \
  { float ar = ur[i], ai = ui[i], br = ur[j], bi = ui[j];          \
    ur[i] = RS2 * (ar - bi); ui[i] = RS2 * (ai + br);              \
    ur[j] = RS2 * (br - ai); ui[j] = RS2 * (bi + ar); }

#define PREF(q)                                                              \
  { float4 a = rsp[q][m0], b2 = rsp[q][m1], c2 = rsp[q][m2], d2 = rsp[q][v]; \
    float t1r = a.x*b2.x - a.y*b2.y, t1i = a.x*b2.y + a.y*b2.x;              \
    float t2r = c2.x*d2.x - c2.y*d2.y, t2i = c2.x*d2.y + c2.y*d2.x;          \
    float u1r = a.z*b2.z - a.w*b2.w, u1i = a.z*b2.w + a.w*b2.z;              \
    float u2r = c2.z*d2.z - c2.w*d2.w, u2i = c2.z*d2.w + c2.w*d2.z;          \
    pf##q = make_float4(t1r*t2r - t1i*t2i, t1r*t2i + t1i*t2r,                \
                        u1r*u2r - u1i*u2i, u1r*u2i + u1i*u2r); }

#define WSTEP(q, PR, PI)                                            \
  { float4 e2 = rsp[q][w];                                          \
    PR = fmaf(pf##q.x, e2.x, PR); PR = fmaf(-pf##q.y, e2.y, PR);    \
    PI = fmaf(pf##q.x, e2.y, PI); PI = fmaf(pf##q.y, e2.x, PI);     \
    PR = fmaf(pf##q.z, e2.z, PR); PR = fmaf(-pf##q.w, e2.w, PR);    \
    PI = fmaf(pf##q.z, e2.w, PI); PI = fmaf(pf##q.w, e2.z, PI); }

__global__ __launch_bounds__(TPB, 8) void qlayer_kernel(
    const float* __restrict__ x,      // [B,8]
    const float* __restrict__ th,     // [12]
    const float* __restrict__ W,      // [S_TOT,10]
    const float* __restrict__ bias,   // [10]
    float* __restrict__ out)          // [B,10]
{
  __shared__ float4 rsp[QG][MODES];   // packed Glynn row-sums, sign pre-folded
  __shared__ float2 uc[MODES][NPH];   // Ucols staging
  __shared__ float2 sc[20];           // (sin,cos) per layer
  __shared__ float  wred[NWAVE][NOUT];

  const int b = blockIdx.x;
  const int t = threadIdx.x;

  // ---------- Phase A0: all 20 sincos in parallel ----------
  if (t < 20) {
    float phi = (t < 12) ? th[t] : x[b * 8 + (t - 12)] * TWO_PI_F;
    float s, c;
    sincosf(phi, &s, &c);
    sc[t] = make_float2(s, c);
  }
  __syncthreads();

  // ---------- Phase A: evolve columns 0..4 of U (threads 0..4) ----------
  if (t < NPH) {
    float ur[MODES], ui[MODES];
    #pragma unroll
    for (int m = 0; m < MODES; ++m) { ur[m] = 0.f; ui[m] = 0.f; }
    ur[t] = 1.f;
    #pragma unroll
    for (int k = 0; k < 20; ++k) {
      const int mode = k % MODES;     // compile-time (k unrolled)
      float sp = sc[k].x, cp = sc[k].y;
      float re = ur[mode] * cp - ui[mode] * sp;
      float im = ur[mode] * sp + ui[mode] * cp;
      ur[mode] = re; ui[mode] = im;
      if ((k & 1) == 0) {             // BS_EVEN
        BFLY(0, 1) BFLY(2, 3) BFLY(4, 5) BFLY(6, 7) BFLY(8, 9) BFLY(10, 11)
      } else {                        // BS_ODD
        BFLY(1, 2) BFLY(3, 4) BFLY(5, 6) BFLY(7, 8) BFLY(9, 10)
      }
    }
    #pragma unroll
    for (int m = 0; m < MODES; ++m) uc[m][t] = make_float2(ur[m], ui[m]);
  }
  __syncthreads();

  // ---------- Phase B: packed row-sums rsp[q][m] for terms k=2q, 2q+1 ----------
  if (t < QG * MODES) {
    const int q = t / MODES;
    const int m = t - q * MODES;
    const int k0 = 2 * q, k1 = 2 * q + 1;
    float r0 = uc[m][0].x, i0 = uc[m][0].y;   // delta_0 = +1
    float r1 = r0, i1 = i0;
    #pragma unroll
    for (int c = 1; c < NPH; ++c) {
      float ux = uc[m][c].x, uy = uc[m][c].y;
      float d0 = ((k0 >> (c - 1)) & 1) ? -1.f : 1.f;
      float d1 = ((k1 >> (c - 1)) & 1) ? -1.f : 1.f;
      r0 = fmaf(d0, ux, r0); i0 = fmaf(d0, uy, i0);
      r1 = fmaf(d1, ux, r1); i1 = fmaf(d1, uy, i1);
    }
    float sg0 = (__popc((unsigned)k0) & 1) ? -1.f : 1.f;
    float sg1 = (__popc((unsigned)k1) & 1) ? -1.f : 1.f;
    rsp[q][m] = make_float4(sg0 * r0, sg0 * i0, sg1 * r1, sg1 * i1);
  }
  __syncthreads();

  // ---------- Phase C: table-scheduled prefix-factorized permanents ----------
  float po[NOUT];
  #pragma unroll
  for (int o = 0; o < NOUT; ++o) po[o] = 0.f;

  const int beg = g_tab.cstart[t];
  const int end = g_tab.cstart[t + 1];
  for (int j = beg; j < end; ++j) {
    const unsigned e = g_tab.pref[j];
    const int sbase = (int)(e >> 16);
    const int m0 = (e >> 12) & 15, m1 = (e >> 8) & 15, m2 = (e >> 4) & 15;
    const int v  = e & 15;

    // 16 prefix Glynn products in 8 NAMED float4 regs
    float4 pf0, pf1, pf2, pf3, pf4, pf5, pf6, pf7;
    PREF(0) PREF(1) PREF(2) PREF(3) PREF(4) PREF(5) PREF(6) PREF(7)

    // norm: pm = prod of run-factorials of the 4-prefix
    int run = 1, pm = 1;
    run = (m1 == m0) ? run + 1 : 1; pm *= run;
    run = (m2 == m1) ? run + 1 : 1; pm *= run;
    run = (v  == m2) ? run + 1 : 1; pm *= run;
    float inv_pm    = 1.0f / (256.0f * (float)pm);   // w > v
    float invn      = inv_pm / (float)(run + 1);     // w == v extends the run

    const float2* wr2 = (const float2*)(W + (size_t)sbase * NOUT);
    for (int w = v; w < MODES; ++w) {
      float pr0 = 0.f, pi0 = 0.f, pr1 = 0.f, pi1 = 0.f;
      WSTEP(0, pr0, pi0) WSTEP(1, pr0, pi0) WSTEP(2, pr0, pi0) WSTEP(3, pr0, pi0)
      WSTEP(4, pr1, pi1) WSTEP(5, pr1, pi1) WSTEP(6, pr1, pi1) WSTEP(7, pr1, pi1)
      float pr = pr0 + pr1, pi = pi0 + pi1;
      float prob = (pr * pr + pi * pi) * invn;
      invn = inv_pm;
      float2 w01 = wr2[0], w23 = wr2[1], w45 = wr2[2], w67 = wr2[3], w89 = wr2[4];
      wr2 += 5;
      po[0] = fmaf(prob, w01.x, po[0]); po[1] = fmaf(prob, w01.y, po[1]);
      po[2] = fmaf(prob, w23.x, po[2]); po[3] = fmaf(prob, w23.y, po[3]);
      po[4] = fmaf(prob, w45.x, po[4]); po[5] = fmaf(prob, w45.y, po[5]);
      po[6] = fmaf(prob, w67.x, po[6]); po[7] = fmaf(prob, w67.y, po[7]);
      po[8] = fmaf(prob, w89.x, po[8]); po[9] = fmaf(prob, w89.y, po[9]);
    }
  }

  // ---------- Phase D: block reduction ----------
  #pragma unroll
  for (int o = 0; o < NOUT; ++o) {
    float v = po[o];
    #pragma unroll
    for (int off = 32; off > 0; off >>= 1) v += __shfl_down(v, off, 64);
    po[o] = v;
  }
  const int lane = t & 63, wave = t >> 6;
  if (lane == 0) {
    #pragma unroll
    for (int o = 0; o < NOUT; ++o) wred[wave][o] = po[o];
  }
  __syncthreads();
  if (t < NOUT) {
    float acc = bias[t];
    #pragma unroll
    for (int w2 = 0; w2 < NWAVE; ++w2) acc += wred[w2][t];
    out[b * NOUT + t] = acc;
  }
}

extern "C" void kernel_launch(void* const* d_in, const int* in_sizes, int n_in,
                              void* d_out, int out_size, void* d_ws, size_t ws_size,
                              hipStream_t stream) {
  (void)n_in; (void)out_size; (void)d_ws; (void)ws_size;
  const float* x    = (const float*)d_in[0];
  const float* th   = (const float*)d_in[1];
  const float* W    = (const float*)d_in[2];
  const float* bias = (const float*)d_in[3];
  float* out        = (float*)d_out;
  const int B = in_sizes[0] / 8;   // 512
  qlayer_kernel<<<B, TPB, 0, stream>>>(x, th, W, bias, out);
}

// Round 5
// 27.581 us; speedup vs baseline: 3.5684x; 3.5684x over previous
//
#include <hip/hip_runtime.h>

// QuantumLayer: boson-sampling distribution + linear head.
//   x:[512,8] f32, thetas:[12] f32, W:[4368,10] f32, b:[10] f32 -> out:[512,10] f32
// Identities:
//   * Columns of U evolve independently under row-ops => evolve only cols 0..4.
//   * Glynn (16 terms, delta_0=+1); sign folded into rs; 2^-4 squared -> 1/256.
//   * Prefix factorization: s-tuples sharing (m0..m3) are contiguous runs.
//   * R5: pair-product LDS table PP[q][78] (all rs_k[a]*rs_k[b], a<=b) =>
//     prefix product = PP[p01]*PP[p2v]: 16 instead of 32 b128 loads/prefix,
//     shorter dep chain, bit-identical arithmetic.
//   * Schedule: constexpr __constant__ table of 1365 prefixes, v-descending
//     (uniform trip counts within a wave), cost-balanced chunks per thread
//     (cost = 16 + 8*(12-v)). Norm via 3-bit code -> 7-entry constant LUT.
//   * R4 lesson: TPB=512, __launch_bounds__(512,2) — NEVER cap VGPRs below
//     live state (R4's (1024,8) => 64-reg cap => 185MB/dispatch scratch).

#define MODES 12
#define NPH   5
#define KG    16
#define QG    8         // KG/2 packed pairs
#define NPAIR 78        // C(12,2)+12 unordered pairs a<=b
#define S_TOT 4368
#define TPB   512
#define NWAVE (TPB / 64)
#define NOUT  10
#define NPREF 1365

#define TWO_PI_F 6.28318530717958647692f
#define RS2      0.70710678118654752440f

// ---------------- compile-time schedule ----------------
constexpr int Cnk(int n, int r) {
  int p = 1;
  for (int i = 0; i < r; ++i) p = p * (n - i) / (i + 1);  // exact stepwise
  return p;
}

struct Tables {
  unsigned       pref[NPREF];     // code<<29 | sbase<<16 | m0<<12 | m1<<8 | m2<<4 | v
  unsigned short cstart[TPB + 1];
  unsigned char  pairs[NPAIR];    // a<<4 | b
};

constexpr Tables make_tables() {
  Tables T{};
  int idx = 0;
  for (int v = 11; v >= 0; --v)
    for (int m0 = 0; m0 <= v; ++m0)
      for (int m1 = m0; m1 <= v; ++m1)
        for (int m2 = m1; m2 <= v; ++m2) {
          int sbase = 0;  // lex rank of (m0,m1,m2,v,v) in CWR(12,5)
          for (int q = 0;  q < m0; ++q) sbase += Cnk(15 - q, 4);
          for (int q = m0; q < m1; ++q) sbase += Cnk(14 - q, 3);
          for (int q = m1; q < m2; ++q) sbase += Cnk(13 - q, 2);
          for (int q = m2; q < v;  ++q) sbase += 12 - q;
          // norm code from (pm, run) of the 4-prefix (only 7 combos exist)
          int r1 = 1, pm = 1;
          r1 = (m1 == m0) ? r1 + 1 : 1; pm *= r1;
          r1 = (m2 == m1) ? r1 + 1 : 1; pm *= r1;
          r1 = (v  == m2) ? r1 + 1 : 1; pm *= r1;
          int code = 0;
          if (pm == 1)       code = 0;
          else if (pm == 2)  code = (r1 == 1) ? 1 : 2;
          else if (pm == 4)  code = 3;
          else if (pm == 6)  code = (r1 == 1) ? 4 : 5;
          else               code = 6;   // pm == 24
          T.pref[idx++] = ((unsigned)code << 29) | ((unsigned)sbase << 16) |
                          ((unsigned)m0 << 12) | ((unsigned)m1 << 8) |
                          ((unsigned)m2 << 4) | (unsigned)v;
        }
  // cost-balanced chunks; cost(entry) = 16 + 8*(12-v)  (b128-load model)
  const long total = 56784;     // 1365*16 + 4368*8
  long cum = 0;
  int ci = 0;
  T.cstart[0] = 0;
  for (int i = 0; i < NPREF; ++i) {
    int v = (int)(T.pref[i] & 15u);
    cum += 16 + 8 * (12 - v);
    while (ci < TPB - 1 && cum * TPB >= (long)(ci + 1) * total)
      T.cstart[++ci] = (unsigned short)(i + 1);
  }
  while (ci < TPB) T.cstart[++ci] = NPREF;
  // unordered pair index table
  int pi = 0;
  for (int a = 0; a < MODES; ++a)
    for (int b = a; b < MODES; ++b)
      T.pairs[pi++] = (unsigned char)((a << 4) | b);
  return T;
}

__constant__ Tables g_tab = make_tables();

// (inv_first, inv_pm) per norm code: inv_pm = 1/(256*pm), inv_first = inv_pm/(run+1)
__constant__ float2 g_normlut[7] = {
  {1.f / 512.f,   1.f / 256.f},    // pm=1,  run=1
  {1.f / 1024.f,  1.f / 512.f},    // pm=2,  run=1
  {1.f / 1536.f,  1.f / 512.f},    // pm=2,  run=2
  {1.f / 3072.f,  1.f / 1024.f},   // pm=4,  run=2
  {1.f / 3072.f,  1.f / 1536.f},   // pm=6,  run=1
  {1.f / 6144.f,  1.f / 1536.f},   // pm=6,  run=3
  {1.f / 30720.f, 1.f / 6144.f},   // pm=24, run=4
};

// ---------------- device kernel ----------------
#define BFLY(i, j)                                                 \
  { float ar = ur[i], ai = ui[i], br = ur[j], bi = ui[j];          \
    ur[i] = RS2 * (ar - bi); ui[i] = RS2 * (ai + br);              \
    ur[j] = RS2 * (br - ai); ui[j] = RS2 * (bi + ar); }

// prefix product from two pair-products (packed k0,k1): pf_q = PP[p01]*PP[p2v]
#define PREF(q)                                                     \
  { float4 A = ppt[q][p01], B = ppt[q][p2v];                        \
    pf##q = make_float4(A.x*B.x - A.y*B.y, A.x*B.y + A.y*B.x,       \
                        A.z*B.z - A.w*B.w, A.z*B.w + A.w*B.z); }

#define WSTEP(q, PR, PI)                                            \
  { float4 e2 = rsp[q][w];                                          \
    PR = fmaf(pf##q.x, e2.x, PR); PR = fmaf(-pf##q.y, e2.y, PR);    \
    PI = fmaf(pf##q.x, e2.y, PI); PI = fmaf(pf##q.y, e2.x, PI);     \
    PR = fmaf(pf##q.z, e2.z, PR); PR = fmaf(-pf##q.w, e2.w, PR);    \
    PI = fmaf(pf##q.z, e2.w, PI); PI = fmaf(pf##q.w, e2.z, PI); }

__global__ __launch_bounds__(TPB, 2) void qlayer_kernel(
    const float* __restrict__ x,      // [B,8]
    const float* __restrict__ th,     // [12]
    const float* __restrict__ W,      // [S_TOT,10]
    const float* __restrict__ bias,   // [10]
    float* __restrict__ out)          // [B,10]
{
  __shared__ float4 rsp[QG][MODES];   // packed Glynn row-sums, sign pre-folded
  __shared__ float4 ppt[QG][NPAIR];   // pair products rs_k[a]*rs_k[b]
  __shared__ float2 uc[MODES][NPH];   // Ucols staging
  __shared__ float2 sc[20];           // (sin,cos) per layer
  __shared__ float  wred[NWAVE][NOUT];

  const int b = blockIdx.x;
  const int t = threadIdx.x;

  // ---------- Phase A0: all 20 sincos in parallel ----------
  if (t < 20) {
    float phi = (t < 12) ? th[t] : x[b * 8 + (t - 12)] * TWO_PI_F;
    float s, c;
    sincosf(phi, &s, &c);
    sc[t] = make_float2(s, c);
  }
  __syncthreads();

  // ---------- Phase A: evolve columns 0..4 of U (threads 0..4) ----------
  if (t < NPH) {
    float ur[MODES], ui[MODES];
    #pragma unroll
    for (int m = 0; m < MODES; ++m) { ur[m] = 0.f; ui[m] = 0.f; }
    ur[t] = 1.f;
    #pragma unroll
    for (int k = 0; k < 20; ++k) {
      const int mode = k % MODES;     // compile-time (k unrolled)
      float sp = sc[k].x, cp = sc[k].y;
      float re = ur[mode] * cp - ui[mode] * sp;
      float im = ur[mode] * sp + ui[mode] * cp;
      ur[mode] = re; ui[mode] = im;
      if ((k & 1) == 0) {             // BS_EVEN
        BFLY(0, 1) BFLY(2, 3) BFLY(4, 5) BFLY(6, 7) BFLY(8, 9) BFLY(10, 11)
      } else {                        // BS_ODD
        BFLY(1, 2) BFLY(3, 4) BFLY(5, 6) BFLY(7, 8) BFLY(9, 10)
      }
    }
    #pragma unroll
    for (int m = 0; m < MODES; ++m) uc[m][t] = make_float2(ur[m], ui[m]);
  }
  __syncthreads();

  // ---------- Phase B: packed row-sums rsp[q][m] for terms k=2q, 2q+1 ----------
  if (t < QG * MODES) {
    const int q = t / MODES;
    const int m = t - q * MODES;
    const int k0 = 2 * q, k1 = 2 * q + 1;
    float r0 = uc[m][0].x, i0 = uc[m][0].y;   // delta_0 = +1
    float r1 = r0, i1 = i0;
    #pragma unroll
    for (int c = 1; c < NPH; ++c) {
      float ux = uc[m][c].x, uy = uc[m][c].y;
      float d0 = ((k0 >> (c - 1)) & 1) ? -1.f : 1.f;
      float d1 = ((k1 >> (c - 1)) & 1) ? -1.f : 1.f;
      r0 = fmaf(d0, ux, r0); i0 = fmaf(d0, uy, i0);
      r1 = fmaf(d1, ux, r1); i1 = fmaf(d1, uy, i1);
    }
    float sg0 = (__popc((unsigned)k0) & 1) ? -1.f : 1.f;
    float sg1 = (__popc((unsigned)k1) & 1) ? -1.f : 1.f;
    rsp[q][m] = make_float4(sg0 * r0, sg0 * i0, sg1 * r1, sg1 * i1);
  }
  __syncthreads();

  // ---------- Phase B2: pair products ppt[q][p] = rs[a]*rs[b] (packed) ----------
  for (int i = t; i < QG * NPAIR; i += TPB) {
    const int q = i / NPAIR;
    const int p = i - q * NPAIR;
    const int ab = (int)g_tab.pairs[p];
    const int a = ab >> 4, b2 = ab & 15;
    float4 A = rsp[q][a], B = rsp[q][b2];
    ppt[q][p] = make_float4(A.x*B.x - A.y*B.y, A.x*B.y + A.y*B.x,
                            A.z*B.z - A.w*B.w, A.z*B.w + A.w*B.z);
  }
  __syncthreads();

  // ---------- Phase C: table-scheduled prefix-factorized permanents ----------
  float po[NOUT];
  #pragma unroll
  for (int o = 0; o < NOUT; ++o) po[o] = 0.f;

  const int beg = g_tab.cstart[t];
  const int end = g_tab.cstart[t + 1];
  for (int j = beg; j < end; ++j) {
    const unsigned e = g_tab.pref[j];
    const int v  = e & 15;
    const int m2 = (e >> 4) & 15;
    const int m1 = (e >> 8) & 15;
    const int m0 = (e >> 12) & 15;
    const int sbase = (int)((e >> 16) & 0x1FFFu);
    const float2 nl = g_normlut[e >> 29];

    // unordered pair indices: off[a] = a*(25-a)/2
    const int p01 = (m0 * (25 - m0)) / 2 + (m1 - m0);
    const int p2v = (m2 * (25 - m2)) / 2 + (v  - m2);

    // 16 prefix Glynn products in 8 NAMED float4 regs (no runtime indexing)
    float4 pf0, pf1, pf2, pf3, pf4, pf5, pf6, pf7;
    PREF(0) PREF(1) PREF(2) PREF(3) PREF(4) PREF(5) PREF(6) PREF(7)

    float invn = nl.x;                 // w == v (extends final run)
    const float2* wr2 = (const float2*)(W + (size_t)sbase * NOUT);
    for (int w = v; w < MODES; ++w) {
      float pr0 = 0.f, pi0 = 0.f, pr1 = 0.f, pi1 = 0.f;
      WSTEP(0, pr0, pi0) WSTEP(1, pr0, pi0) WSTEP(2, pr0, pi0) WSTEP(3, pr0, pi0)
      WSTEP(4, pr1, pi1) WSTEP(5, pr1, pi1) WSTEP(6, pr1, pi1) WSTEP(7, pr1, pi1)
      float pr = pr0 + pr1, pi = pi0 + pi1;
      float prob = (pr * pr + pi * pi) * invn;
      invn = nl.y;                     // w > v
      float2 w01 = wr2[0], w23 = wr2[1], w45 = wr2[2], w67 = wr2[3], w89 = wr2[4];
      wr2 += 5;
      po[0] = fmaf(prob, w01.x, po[0]); po[1] = fmaf(prob, w01.y, po[1]);
      po[2] = fmaf(prob, w23.x, po[2]); po[3] = fmaf(prob, w23.y, po[3]);
      po[4] = fmaf(prob, w45.x, po[4]); po[5] = fmaf(prob, w45.y, po[5]);
      po[6] = fmaf(prob, w67.x, po[6]); po[7] = fmaf(prob, w67.y, po[7]);
      po[8] = fmaf(prob, w89.x, po[8]); po[9] = fmaf(prob, w89.y, po[9]);
    }
  }

  // ---------- Phase D: block reduction ----------
  #pragma unroll
  for (int o = 0; o < NOUT; ++o) {
    float v = po[o];
    #pragma unroll
    for (int off = 32; off > 0; off >>= 1) v += __shfl_down(v, off, 64);
    po[o] = v;
  }
  const int lane = t & 63, wave = t >> 6;
  if (lane == 0) {
    #pragma unroll
    for (int o = 0; o < NOUT; ++o) wred[wave][o] = po[o];
  }
  __syncthreads();
  if (t < NOUT) {
    float acc = bias[t];
    #pragma unroll
    for (int w2 = 0; w2 < NWAVE; ++w2) acc += wred[w2][t];
    out[b * NOUT + t] = acc;
  }
}

extern "C" void kernel_launch(void* const* d_in, const int* in_sizes, int n_in,
                              void* d_out, int out_size, void* d_ws, size_t ws_size,
                              hipStream_t stream) {
  (void)n_in; (void)out_size; (void)d_ws; (void)ws_size;
  const float* x    = (const float*)d_in[0];
  const float* th   = (const float*)d_in[1];
  const float* W    = (const float*)d_in[2];
  const float* bias = (const float*)d_in[3];
  float* out        = (float*)d_out;
  const int B = in_sizes[0] / 8;   // 512
  qlayer_kernel<<<B, TPB, 0, stream>>>(x, th, W, bias, out);
}